// Round 4
// baseline (1592.923 us; speedup 1.0000x reference)
//
#include <hip/hip_runtime.h>
#include <math.h>

#define N_NODES   50000
#define N_EDGES   800000
#define BASIS     64
#define HIDDEN_RO 128
#define N_GRAPHS  512
#define T_ITERS   3
#define R_NODES   4                       // nodes per wave in k_mp_win
#define MP_BLOCKS (N_NODES / R_NODES / 4) // 3125 blocks = 12500 waves, exact

typedef short s8 __attribute__((ext_vector_type(8)));   // 8 bf16 in 4 VGPRs
typedef float f4 __attribute__((ext_vector_type(4)));

#define MFMA16(a, b, c) __builtin_amdgcn_mfma_f32_16x16x32_bf16(a, b, c, 0, 0, 0)

// tanh(x) = 1 - 2/(e^{2x}+1); overflow-safe both directions, tanh(0)=0 exactly.
__device__ __forceinline__ float fast_tanh(float x) {
    float e = __expf(2.0f * x);
    return 1.0f - 2.0f / (e + 1.0f);
}

__device__ __forceinline__ f4 splat4(float x) { f4 v; v[0]=x; v[1]=x; v[2]=x; v[3]=x; return v; }

// Split 8 fp32 into bf16 hi (truncation) + bf16 lo (residual) — proven R3, absmax 0.0625.
__device__ __forceinline__ void split8(const float* x, s8& hi, s8& lo) {
    union { unsigned a[4]; s8 v; } H, L;
    #pragma unroll
    for (int j = 0; j < 4; ++j) {
        float e0 = x[2*j], e1 = x[2*j+1];
        unsigned u0 = __float_as_uint(e0), u1 = __float_as_uint(e1);
        H.a[j] = (u0 >> 16) | (u1 & 0xFFFF0000u);
        float l0 = e0 - __uint_as_float(u0 & 0xFFFF0000u);   // exact
        float l1 = e1 - __uint_as_float(u1 & 0xFFFF0000u);
        L.a[j] = (__float_as_uint(l0) >> 16) | (__float_as_uint(l1) & 0xFFFF0000u);
    }
    hi = H.v; lo = L.v;
}

// B-frags for 64x64 row-major W: whi/wlo[ks][g]; lane holds k=(lane>>4)*8+j, n=lane&15.
__device__ __forceinline__ void load_wfrags(const float* __restrict__ W, int lane,
                                            s8 whi[2][4], s8 wlo[2][4]) {
    int q = lane >> 4, c = lane & 15;
    #pragma unroll
    for (int ks = 0; ks < 2; ++ks)
        #pragma unroll
        for (int g = 0; g < 4; ++g) {
            float t[8];
            #pragma unroll
            for (int j = 0; j < 8; ++j)
                t[j] = W[(ks*32 + q*8 + j) * 64 + g*16 + c];
            split8(t, whi[ks][g], wlo[ks][g]);
        }
}

// C[n,:] = embed[Z[n],:]
__global__ void k_init_C(const int* __restrict__ Z, const float* __restrict__ embed,
                         float* __restrict__ C) {
    int i = blockIdx.x * blockDim.x + threadIdx.x;
    if (i >= N_NODES * BASIS) return;
    int n = i >> 6, c = i & 63;
    C[i] = embed[Z[n] * BASIS + c];
}

// out[r,:] = in[r,:] @ W + b — sequential rows (CF build). Proven R3.
__global__ __launch_bounds__(256) void k_gemm64(const float* __restrict__ in,
        const float* __restrict__ W, const float* __restrict__ b,
        float* __restrict__ out, int rows) {
    int lane = threadIdx.x & 63, wv = threadIdx.x >> 6;
    int q = lane >> 4, c = lane & 15;
    s8 whi[2][4], wlo[2][4];
    load_wfrags(W, lane, whi, wlo);
    float bias[4];
    #pragma unroll
    for (int g = 0; g < 4; ++g) bias[g] = b[g*16 + c];
    int chunks = (rows + 15) >> 4;
    int wave = blockIdx.x * 4 + wv, nw = gridDim.x * 4;
    for (int ch = wave; ch < chunks; ch += nw) {
        int base = ch << 4;
        int row = base + c;
        bool valid = row < rows;
        const float4* ip = (const float4*)(in + (size_t)(valid ? row : 0) * 64);
        s8 ahi[2], alo[2];
        #pragma unroll
        for (int ks = 0; ks < 2; ++ks) {
            float4 a0 = ip[ks*8 + q*2 + 0];
            float4 a1 = ip[ks*8 + q*2 + 1];
            float xs[8] = {a0.x,a0.y,a0.z,a0.w, a1.x,a1.y,a1.z,a1.w};
            if (!valid) {
                #pragma unroll
                for (int j = 0; j < 8; ++j) xs[j] = 0.0f;
            }
            split8(xs, ahi[ks], alo[ks]);
        }
        f4 acc[4];
        #pragma unroll
        for (int g = 0; g < 4; ++g) acc[g] = splat4(bias[g]);
        #pragma unroll
        for (int ks = 0; ks < 2; ++ks)
            #pragma unroll
            for (int g = 0; g < 4; ++g) {
                acc[g] = MFMA16(ahi[ks], whi[ks][g], acc[g]);
                acc[g] = MFMA16(ahi[ks], wlo[ks][g], acc[g]);
                acc[g] = MFMA16(alo[ks], whi[ks][g], acc[g]);
            }
        #pragma unroll
        for (int g = 0; g < 4; ++g)
            #pragma unroll
            for (int r = 0; r < 4; ++r) {
                int ro = base + q*4 + r;
                if (ro < rows) out[(size_t)ro * 64 + g*16 + c] = acc[g][r];
            }
    }
}

// DF build in CSR slot order: DF[p,:] = ea[meta[p].x,:] @ dfW + dfb.
// Gather-read rows (random 256B), sequential write -> k_mp streams DF.
__global__ __launch_bounds__(256) void k_gemm64g(const float* __restrict__ in,
        const int4* __restrict__ meta, const float* __restrict__ W,
        const float* __restrict__ b, float* __restrict__ out) {
    int lane = threadIdx.x & 63, wv = threadIdx.x >> 6;
    int q = lane >> 4, c = lane & 15;
    s8 whi[2][4], wlo[2][4];
    load_wfrags(W, lane, whi, wlo);
    float bias[4];
    #pragma unroll
    for (int g = 0; g < 4; ++g) bias[g] = b[g*16 + c];
    const int windows = N_EDGES / 16;     // exact
    int wave = blockIdx.x * 4 + wv, nw = gridDim.x * 4;
    for (int wb = wave; wb < windows; wb += nw) {
        int slot = wb * 16 + c;
        int e = meta[slot].x;
        const float4* ip = (const float4*)(in + (size_t)e * 64);
        s8 ahi[2], alo[2];
        #pragma unroll
        for (int ks = 0; ks < 2; ++ks) {
            float4 a0 = ip[ks*8 + q*2 + 0];
            float4 a1 = ip[ks*8 + q*2 + 1];
            float xs[8] = {a0.x,a0.y,a0.z,a0.w, a1.x,a1.y,a1.z,a1.w};
            split8(xs, ahi[ks], alo[ks]);
        }
        f4 acc[4];
        #pragma unroll
        for (int g = 0; g < 4; ++g) acc[g] = splat4(bias[g]);
        #pragma unroll
        for (int ks = 0; ks < 2; ++ks)
            #pragma unroll
            for (int g = 0; g < 4; ++g) {
                acc[g] = MFMA16(ahi[ks], whi[ks][g], acc[g]);
                acc[g] = MFMA16(ahi[ks], wlo[ks][g], acc[g]);
                acc[g] = MFMA16(alo[ks], whi[ks][g], acc[g]);
            }
        #pragma unroll
        for (int g = 0; g < 4; ++g)
            #pragma unroll
            for (int r = 0; r < 4; ++r)
                out[(size_t)(wb*16 + q*4 + r) * 64 + g*16 + c] = acc[g][r];
    }
}

// ---- CSR build ----
__global__ void k_hist(const int* __restrict__ dst, int* __restrict__ deg) {
    int e = blockIdx.x * blockDim.x + threadIdx.x;
    if (e < N_EDGES) atomicAdd(&deg[dst[e]], 1);
}

__global__ void k_scan(const int* __restrict__ deg, int* __restrict__ off,
                       int* __restrict__ cursor) {
    __shared__ int wsum[16];
    __shared__ int run_s;
    int t = threadIdx.x, lane = t & 63, w = t >> 6;
    if (t == 0) run_s = 0;
    __syncthreads();
    for (int base = 0; base < N_NODES; base += 1024) {
        int i = base + t;
        int v = (i < N_NODES) ? deg[i] : 0;
        int s = v;
        #pragma unroll
        for (int ofs = 1; ofs < 64; ofs <<= 1) {
            int tmp = __shfl_up(s, ofs, 64);
            if (lane >= ofs) s += tmp;
        }
        if (lane == 63) wsum[w] = s;
        __syncthreads();
        if (w == 0) {
            int x = (lane < 16) ? wsum[lane] : 0;
            #pragma unroll
            for (int ofs = 1; ofs < 16; ofs <<= 1) {
                int tmp = __shfl_up(x, ofs, 64);
                if (lane >= ofs) x += tmp;
            }
            if (lane < 16) wsum[lane] = x;
        }
        __syncthreads();
        int run = run_s;
        int wex = (w == 0) ? 0 : wsum[w - 1];
        int incl = run + wex + s;
        if (i < N_NODES) { off[i] = incl - v; cursor[i] = incl - v; }
        __syncthreads();
        if (t == 1023) run_s = incl;
        __syncthreads();
    }
    if (t == 0) off[N_NODES] = run_s;
}

// meta[p] = {edge id, src[e], dst[e], 0} — one 16B scattered store per edge.
__global__ void k_fill(const int* __restrict__ src, const int* __restrict__ dst,
                       int* __restrict__ cursor, int4* __restrict__ meta) {
    int e = blockIdx.x * blockDim.x + threadIdx.x;
    if (e < N_EDGES) {
        int d = dst[e], s = src[e];
        int p = atomicAdd(&cursor[d], 1);
        meta[p] = make_int4(e, s, d, 0);
    }
}

// ---- fused message+aggregate over flat slot windows ----
// Wave owns nodes [n0, n0+4) and slots [off[n0], off[n0+4)). 16-slot windows
// span node boundaries; per-window MFMA -> tanh -> ds_add into wave-private
// LDS accumulator (row = local node, via shuffle); flush with plain C +=.
__global__ __launch_bounds__(256) void k_mp_win(const float* __restrict__ CF,
        const float* __restrict__ DF, const float* __restrict__ fcW,
        const int4* __restrict__ meta, const int* __restrict__ off,
        float* __restrict__ C) {
    __shared__ float acc[4][R_NODES + 1][64];   // +1 dump row for invalid slots
    int lane = threadIdx.x & 63, wv = threadIdx.x >> 6;
    int q = lane >> 4, c = lane & 15;
    s8 whi[2][4], wlo[2][4];
    load_wfrags(fcW, lane, whi, wlo);
    int wave = blockIdx.x * 4 + wv;             // grid exact: 12500 waves
    int n0 = wave * R_NODES;
    int sbeg = off[n0], send = off[n0 + R_NODES];
    #pragma unroll
    for (int r = 0; r <= R_NODES; ++r) acc[wv][r][lane] = 0.0f;
    __builtin_amdgcn_wave_barrier();
    int nwin = (send - sbeg + 15) >> 4;

    int4 m0 = make_int4(0,0,0,0), m1 = m0;
    float4 dc[4], cf[4];
    if (nwin > 0) {
        int sl0 = sbeg + c; if (sl0 >= send) sl0 = send - 1;
        m0 = meta[sl0];
        if (nwin > 1) {
            int sl1 = sbeg + 16 + c; if (sl1 >= send) sl1 = send - 1;
            m1 = meta[sl1];
        }
        const float4* dp = (const float4*)(DF + (size_t)sl0 * 64);
        dc[0] = dp[q*2]; dc[1] = dp[q*2+1]; dc[2] = dp[8+q*2]; dc[3] = dp[8+q*2+1];
        const float4* cp = (const float4*)(CF + (size_t)m0.y * 64);
        cf[0] = cp[q*2]; cf[1] = cp[q*2+1]; cf[2] = cp[8+q*2]; cf[3] = cp[8+q*2+1];
    }
    #pragma unroll 1
    for (int w = 0; w < nwin; ++w) {
        int base = sbeg + (w << 4);
        bool valid = (base + c) < send;
        int nloc = valid ? (m0.z - n0) : R_NODES;
        // prefetch window w+1 (m1 issued one full iteration ago), meta w+2
        float4 dn[4], cn[4];
        int4 m2 = m1;
        if (w + 1 < nwin) {
            int sl = base + 16 + c; if (sl >= send) sl = send - 1;
            const float4* dp = (const float4*)(DF + (size_t)sl * 64);
            dn[0] = dp[q*2]; dn[1] = dp[q*2+1]; dn[2] = dp[8+q*2]; dn[3] = dp[8+q*2+1];
            const float4* cp = (const float4*)(CF + (size_t)m1.y * 64);
            cn[0] = cp[q*2]; cn[1] = cp[q*2+1]; cn[2] = cp[8+q*2]; cn[3] = cp[8+q*2+1];
            if (w + 2 < nwin) {
                int s2 = base + 32 + c; if (s2 >= send) s2 = send - 1;
                m2 = meta[s2];
            }
        }
        // compute window w
        s8 ahi[2], alo[2];
        {
            float xs[8] = {cf[0].x*dc[0].x, cf[0].y*dc[0].y, cf[0].z*dc[0].z, cf[0].w*dc[0].w,
                           cf[1].x*dc[1].x, cf[1].y*dc[1].y, cf[1].z*dc[1].z, cf[1].w*dc[1].w};
            if (!valid) {
                #pragma unroll
                for (int j = 0; j < 8; ++j) xs[j] = 0.0f;
            }
            split8(xs, ahi[0], alo[0]);
            float ys[8] = {cf[2].x*dc[2].x, cf[2].y*dc[2].y, cf[2].z*dc[2].z, cf[2].w*dc[2].w,
                           cf[3].x*dc[3].x, cf[3].y*dc[3].y, cf[3].z*dc[3].z, cf[3].w*dc[3].w};
            if (!valid) {
                #pragma unroll
                for (int j = 0; j < 8; ++j) ys[j] = 0.0f;
            }
            split8(ys, ahi[1], alo[1]);
        }
        f4 d[4];
        #pragma unroll
        for (int g = 0; g < 4; ++g) d[g] = splat4(0.0f);
        #pragma unroll
        for (int ks = 0; ks < 2; ++ks)
            #pragma unroll
            for (int g = 0; g < 4; ++g) {
                d[g] = MFMA16(ahi[ks], whi[ks][g], d[g]);
                d[g] = MFMA16(ahi[ks], wlo[ks][g], d[g]);
                d[g] = MFMA16(alo[ks], whi[ks][g], d[g]);
            }
        // D row (q*4+r): its local-node id lives in lane q*16 + (q*4+r)
        #pragma unroll
        for (int r = 0; r < 4; ++r) {
            int nl = __shfl(nloc, q*16 + q*4 + r, 64);
            #pragma unroll
            for (int g = 0; g < 4; ++g)
                atomicAdd(&acc[wv][nl][g*16 + c], fast_tanh(d[g][r]));
        }
        m0 = m1; m1 = m2;
        #pragma unroll
        for (int i = 0; i < 4; ++i) { dc[i] = dn[i]; cf[i] = cn[i]; }
    }
    __syncthreads();
    #pragma unroll
    for (int r = 0; r < R_NODES; ++r) {
        size_t ci = (size_t)(n0 + r) * 64 + lane;
        C[ci] += acc[wv][r][lane];
    }
}

// ---- fallback edge kernel (only if ws too small; never expected) ----
__global__ __launch_bounds__(256) void k_edge_fb(const float* __restrict__ CF,
        const float* __restrict__ ea, const float* __restrict__ dfW,
        const float* __restrict__ dfb, const float* __restrict__ fcW,
        const int* __restrict__ src, const int* __restrict__ dst,
        float* __restrict__ C) {
    int e = blockIdx.x * blockDim.x + threadIdx.x;
    if (e >= N_EDGES) return;
    int s = src[e], d = dst[e];
    float dfeat[BASIS];
    #pragma unroll
    for (int c = 0; c < BASIS; ++c) dfeat[c] = dfb[c];
    const float4* ea4 = (const float4*)(ea + (size_t)e * BASIS);
    #pragma unroll
    for (int k0 = 0; k0 < 16; ++k0) {
        float4 xv = ea4[k0];
        #pragma unroll
        for (int c = 0; c < BASIS; ++c)
            dfeat[c] += xv.x * dfW[(4*k0+0)*64+c] + xv.y * dfW[(4*k0+1)*64+c]
                      + xv.z * dfW[(4*k0+2)*64+c] + xv.w * dfW[(4*k0+3)*64+c];
    }
    const float4* cf4 = (const float4*)(CF + (size_t)s * BASIS);
    float acc[BASIS];
    #pragma unroll
    for (int c = 0; c < BASIS; ++c) acc[c] = 0.0f;
    #pragma unroll
    for (int k0 = 0; k0 < 16; ++k0) {
        float4 a = cf4[k0];
        float x0 = a.x * dfeat[4*k0+0], x1 = a.y * dfeat[4*k0+1];
        float x2 = a.z * dfeat[4*k0+2], x3 = a.w * dfeat[4*k0+3];
        #pragma unroll
        for (int c = 0; c < BASIS; ++c)
            acc[c] += x0 * fcW[(4*k0+0)*64+c] + x1 * fcW[(4*k0+1)*64+c]
                    + x2 * fcW[(4*k0+2)*64+c] + x3 * fcW[(4*k0+3)*64+c];
    }
    float* crow = C + (size_t)d * BASIS;
    #pragma unroll
    for (int c = 0; c < BASIS; ++c) atomicAdd(&crow[c], fast_tanh(acc[c]));
}

// ---- readout: wave per node, W1 in LDS ----
__global__ __launch_bounds__(256) void k_readout2(const float* __restrict__ C,
        const float* __restrict__ W1, const float* __restrict__ b1,
        const float* __restrict__ W2, const float* __restrict__ b2,
        const int* __restrict__ batch, float* __restrict__ out) {
    __shared__ float w1[BASIS * HIDDEN_RO];   // 32 KB
    __shared__ float xbuf[4][64];
    int t = threadIdx.x;
    for (int i = t; i < BASIS * HIDDEN_RO; i += 256) w1[i] = W1[i];
    __syncthreads();
    int lane = t & 63, wv = t >> 6;
    float b1a = b1[lane], b1b = b1[64 + lane];
    float4 w2a = ((const float4*)W2)[lane];
    float4 w2b = ((const float4*)W2)[64 + lane];
    int wave = blockIdx.x * 4 + wv;
    int nw   = gridDim.x * 4;
    for (int n = wave; n < N_NODES; n += nw) {
        float x = C[(size_t)n * 64 + lane];
        xbuf[wv][lane] = x;
        __builtin_amdgcn_wave_barrier();
        const float4* xb = (const float4*)xbuf[wv];
        float sa = b1a, sb = b1b;
        #pragma unroll
        for (int k4 = 0; k4 < 16; ++k4) {
            float4 xv = xb[k4];
            const float* r0 = &w1[(4*k4 + 0) * HIDDEN_RO];
            const float* r1 = &w1[(4*k4 + 1) * HIDDEN_RO];
            const float* r2 = &w1[(4*k4 + 2) * HIDDEN_RO];
            const float* r3 = &w1[(4*k4 + 3) * HIDDEN_RO];
            sa += xv.x * r0[lane]      + xv.y * r1[lane]
                + xv.z * r2[lane]      + xv.w * r3[lane];
            sb += xv.x * r0[64 + lane] + xv.y * r1[64 + lane]
                + xv.z * r2[64 + lane] + xv.w * r3[64 + lane];
        }
        float ha = fast_tanh(sa), hb = fast_tanh(sb);
        float v0 = ha * w2a.x + hb * w2b.x;
        float v1 = ha * w2a.y + hb * w2b.y;
        float v2 = ha * w2a.z + hb * w2b.z;
        float v3 = ha * w2a.w + hb * w2b.w;
        #pragma unroll
        for (int ofs = 32; ofs >= 1; ofs >>= 1) {
            v0 += __shfl_down(v0, ofs, 64);
            v1 += __shfl_down(v1, ofs, 64);
            v2 += __shfl_down(v2, ofs, 64);
            v3 += __shfl_down(v3, ofs, 64);
        }
        if (lane == 0) {
            int g = batch[n];
            atomicAdd(&out[(size_t)g * 4 + 0], v0);
            atomicAdd(&out[(size_t)g * 4 + 1], v1);
            atomicAdd(&out[(size_t)g * 4 + 2], v2);
            atomicAdd(&out[(size_t)g * 4 + 3], v3);
        }
        __builtin_amdgcn_wave_barrier();
    }
}

extern "C" void kernel_launch(void* const* d_in, const int* in_sizes, int n_in,
                              void* d_out, int out_size, void* d_ws, size_t ws_size,
                              hipStream_t stream) {
    // Z, edge_index, edge_attr, batch, embed, cfW, cfb, dfW, dfb, fcW, W1, b1, W2, b2
    const int*   Z     = (const int*)d_in[0];
    const int*   ei    = (const int*)d_in[1];
    const float* ea    = (const float*)d_in[2];
    const int*   batch = (const int*)d_in[3];
    const float* embed = (const float*)d_in[4];
    const float* cfW   = (const float*)d_in[5];
    const float* cfb   = (const float*)d_in[6];
    const float* dfW   = (const float*)d_in[7];
    const float* dfb   = (const float*)d_in[8];
    const float* fcW   = (const float*)d_in[9];
    const float* W1    = (const float*)d_in[10];
    const float* b1    = (const float*)d_in[11];
    const float* W2    = (const float*)d_in[12];
    const float* b2    = (const float*)d_in[13];
    const int* src = ei;
    const int* dst = ei + N_EDGES;
    float* out = (float*)d_out;

    const size_t bC = (size_t)N_NODES * BASIS * sizeof(float);   // 12.8 MB
    const size_t bM = (size_t)N_EDGES * sizeof(int4);            // 12.8 MB
    const size_t bO = (size_t)(N_NODES + 1) * sizeof(int);
    char* p = (char*)d_ws;
    float* C      = (float*)p;  p += bC;
    float* CF     = (float*)p;  p += bC;
    int4*  meta   = (int4*)p;   p += bM;
    int*   deg    = (int*)p;    p += bO;
    int*   off    = (int*)p;    p += bO;
    int*   cursor = (int*)p;    p += bO;
    float* DF     = (float*)p;
    const size_t need = (size_t)(p - (char*)d_ws) + (size_t)N_EDGES * BASIS * sizeof(float);
    const bool full = ws_size >= need;   // ~244 MB

    hipMemsetAsync(d_out, 0, (size_t)out_size * sizeof(float), stream);
    k_init_C<<<(N_NODES * BASIS + 255) / 256, 256, 0, stream>>>(Z, embed, C);

    if (full) {
        hipMemsetAsync(deg, 0, bO, stream);
        k_hist<<<(N_EDGES + 255) / 256, 256, 0, stream>>>(dst, deg);
        k_scan<<<1, 1024, 0, stream>>>(deg, off, cursor);
        k_fill<<<(N_EDGES + 255) / 256, 256, 0, stream>>>(src, dst, cursor, meta);
        k_gemm64g<<<4096, 256, 0, stream>>>(ea, meta, dfW, dfb, DF);
        for (int t = 0; t < T_ITERS; ++t) {
            k_gemm64<<<800, 256, 0, stream>>>(C, cfW, cfb, CF, N_NODES);
            k_mp_win<<<MP_BLOCKS, 256, 0, stream>>>(CF, DF, fcW, meta, off, C);
        }
    } else {
        for (int t = 0; t < T_ITERS; ++t) {
            k_gemm64<<<800, 256, 0, stream>>>(C, cfW, cfb, CF, N_NODES);
            k_edge_fb<<<(N_EDGES + 255) / 256, 256, 0, stream>>>(CF, ea, dfW, dfb, fcW, src, dst, C);
        }
    }

    k_readout2<<<512, 256, 0, stream>>>(C, W1, b1, W2, b2, batch, out);
}

// Round 5
// 926.193 us; speedup vs baseline: 1.7199x; 1.7199x over previous
//
#include <hip/hip_runtime.h>
#include <math.h>

#define N_NODES   50000
#define N_EDGES   800000
#define BASIS     64
#define HIDDEN_RO 128
#define N_GRAPHS  512
#define T_ITERS   3

typedef short s8 __attribute__((ext_vector_type(8)));   // 8 bf16 in 4 VGPRs
typedef float f4 __attribute__((ext_vector_type(4)));

#define MFMA16(a, b, c) __builtin_amdgcn_mfma_f32_16x16x32_bf16(a, b, c, 0, 0, 0)

// tanh(x) = 1 - 2/(e^{2x}+1); overflow-safe both directions, tanh(0)=0 exactly.
__device__ __forceinline__ float fast_tanh(float x) {
    float e = __expf(2.0f * x);
    return 1.0f - 2.0f / (e + 1.0f);
}

__device__ __forceinline__ f4 splat4(float x) { f4 v; v[0]=x; v[1]=x; v[2]=x; v[3]=x; return v; }

// Split 8 fp32 into bf16 hi (truncation) + bf16 lo (residual) — proven R3, absmax 0.0625.
__device__ __forceinline__ void split8(const float* x, s8& hi, s8& lo) {
    union { unsigned a[4]; s8 v; } H, L;
    #pragma unroll
    for (int j = 0; j < 4; ++j) {
        float e0 = x[2*j], e1 = x[2*j+1];
        unsigned u0 = __float_as_uint(e0), u1 = __float_as_uint(e1);
        H.a[j] = (u0 >> 16) | (u1 & 0xFFFF0000u);
        float l0 = e0 - __uint_as_float(u0 & 0xFFFF0000u);   // exact
        float l1 = e1 - __uint_as_float(u1 & 0xFFFF0000u);
        L.a[j] = (__float_as_uint(l0) >> 16) | (__float_as_uint(l1) & 0xFFFF0000u);
    }
    hi = H.v; lo = L.v;
}

// ---- W frag pre-pack: img[f*64+lane], f = ks*4+g (hi), 8+ks*4+g (lo); 16 KB/matrix ----
__device__ __forceinline__ void packW_dev(const float* __restrict__ W, s8* __restrict__ img, int t) {
    int lane = t & 63, q = lane >> 4, c = lane & 15;
    int f0 = (t >> 6) * 2;
    #pragma unroll
    for (int f = f0; f < f0 + 2; ++f) {          // f in 0..7 across the 4 sub-groups
        int ks = f >> 2, g = f & 3;
        float tv[8];
        #pragma unroll
        for (int j = 0; j < 8; ++j)
            tv[j] = W[(ks*32 + q*8 + j) * 64 + g*16 + c];
        s8 hi, lo;
        split8(tv, hi, lo);
        img[f * 64 + lane]       = hi;
        img[(8 + f) * 64 + lane] = lo;
    }
}
__global__ void k_packW(const float* __restrict__ W0, const float* __restrict__ W1,
                        const float* __restrict__ W2, s8* __restrict__ i0,
                        s8* __restrict__ i1, s8* __restrict__ i2) {
    int b = blockIdx.x, t = threadIdx.x;
    if (b == 0) packW_dev(W0, i0, t);
    else if (b == 1) packW_dev(W1, i1, t);
    else packW_dev(W2, i2, t);
}

// C init + degree histogram fused
__global__ void k_init_hist(const int* __restrict__ Z, const float* __restrict__ embed,
                            float* __restrict__ C, const int* __restrict__ dst,
                            int* __restrict__ deg) {
    int i = blockIdx.x * blockDim.x + threadIdx.x;
    if (i < N_NODES * BASIS) { int n = i >> 6, c = i & 63; C[i] = embed[Z[n] * 64 + c]; }
    if (i < N_EDGES) atomicAdd(&deg[dst[i]], 1);
}

// single-block shuffle scan
__global__ void k_scan(const int* __restrict__ deg, int* __restrict__ off,
                       int* __restrict__ cursor) {
    __shared__ int wsum[16];
    __shared__ int run_s;
    int t = threadIdx.x, lane = t & 63, w = t >> 6;
    if (t == 0) run_s = 0;
    __syncthreads();
    for (int base = 0; base < N_NODES; base += 1024) {
        int i = base + t;
        int v = (i < N_NODES) ? deg[i] : 0;
        int s = v;
        #pragma unroll
        for (int ofs = 1; ofs < 64; ofs <<= 1) {
            int tmp = __shfl_up(s, ofs, 64);
            if (lane >= ofs) s += tmp;
        }
        if (lane == 63) wsum[w] = s;
        __syncthreads();
        if (w == 0) {
            int x = (lane < 16) ? wsum[lane] : 0;
            #pragma unroll
            for (int ofs = 1; ofs < 16; ofs <<= 1) {
                int tmp = __shfl_up(x, ofs, 64);
                if (lane >= ofs) x += tmp;
            }
            if (lane < 16) wsum[lane] = x;
        }
        __syncthreads();
        int run = run_s;
        int wex = (w == 0) ? 0 : wsum[w - 1];
        int incl = run + wex + s;
        if (i < N_NODES) { off[i] = incl - v; cursor[i] = incl - v; }
        __syncthreads();
        if (t == 1023) run_s = incl;
        __syncthreads();
    }
    if (t == 0) off[N_NODES] = run_s;
}

// slot_e[p]=edge, slot_s[p]=src — slot-ordered flat arrays (no indirection in k_mp)
__global__ void k_fill(const int* __restrict__ src, const int* __restrict__ dst,
                       int* __restrict__ cursor, int* __restrict__ slot_e,
                       int* __restrict__ slot_s) {
    int e = blockIdx.x * blockDim.x + threadIdx.x;
    if (e < N_EDGES) {
        int d = dst[e], s = src[e];
        int p = atomicAdd(&cursor[d], 1);
        slot_e[p] = e;
        slot_s[p] = s;
    }
}

// ---- generic 64x64 linear via MFMA, W frags from LDS ----
// MODE 0: out[r,:] = in[r,:]@W + b, sequential rows.
// MODE 1: out[slot,:] = in[slot_e[slot],:]@W + b (DF build in CSR slot order).
template <int MODE>
__global__ __launch_bounds__(256, 4) void k_gemm64L(const float* __restrict__ in,
        const s8* __restrict__ wimg, const float* __restrict__ b,
        const int* __restrict__ slot_e, float* __restrict__ out, int rows) {
    __shared__ s8 LW[1024];   // 16 KB
    int t = threadIdx.x;
    for (int i = t; i < 1024; i += 256) LW[i] = wimg[i];
    __syncthreads();
    int lane = t & 63, wv = t >> 6, q = lane >> 4, c = lane & 15;
    float bias[4];
    #pragma unroll
    for (int g = 0; g < 4; ++g) bias[g] = b[g*16 + c];
    int chunks = (rows + 15) >> 4;
    int wave = blockIdx.x * 4 + wv, nw = gridDim.x * 4;
    for (int ch = wave; ch < chunks; ch += nw) {
        int base = ch << 4;
        int row = base + c;
        bool valid = row < rows;
        int r = valid ? row : 0;
        if (MODE == 1) r = slot_e[valid ? row : base];
        const float4* ip = (const float4*)(in + (size_t)r * 64);
        s8 ahi[2], alo[2];
        #pragma unroll
        for (int ks = 0; ks < 2; ++ks) {
            float4 a0 = ip[ks*8 + q*2 + 0];
            float4 a1 = ip[ks*8 + q*2 + 1];
            float xs[8] = {a0.x,a0.y,a0.z,a0.w, a1.x,a1.y,a1.z,a1.w};
            if (!valid) {
                #pragma unroll
                for (int j = 0; j < 8; ++j) xs[j] = 0.0f;
            }
            split8(xs, ahi[ks], alo[ks]);
        }
        f4 acc[4];
        #pragma unroll
        for (int g = 0; g < 4; ++g) acc[g] = splat4(bias[g]);
        #pragma unroll
        for (int ks = 0; ks < 2; ++ks)
            #pragma unroll
            for (int g = 0; g < 4; ++g) {
                s8 wh = LW[(ks*4 + g) * 64 + lane];
                s8 wl = LW[(8 + ks*4 + g) * 64 + lane];
                acc[g] = MFMA16(ahi[ks], wh, acc[g]);
                acc[g] = MFMA16(ahi[ks], wl, acc[g]);
                acc[g] = MFMA16(alo[ks], wh, acc[g]);
            }
        #pragma unroll
        for (int g = 0; g < 4; ++g)
            #pragma unroll
            for (int r2 = 0; r2 < 4; ++r2) {
                int ro = base + q*4 + r2;
                if (ro < rows) out[(size_t)ro * 64 + g*16 + c] = acc[g][r2];
            }
    }
}

// ---- fused message+aggregate: R3 structure + LDS W + slot-ordered DF/src ----
__global__ __launch_bounds__(256, 4) void k_mp5(const float* __restrict__ CF,
        const float* __restrict__ DF, const s8* __restrict__ wimg,
        const int* __restrict__ slot_s, const int* __restrict__ off,
        float* __restrict__ C) {
    __shared__ s8 LW[1024];   // 16 KB
    int t = threadIdx.x;
    for (int i = t; i < 1024; i += 256) LW[i] = wimg[i];
    __syncthreads();
    int lane = t & 63, wv = t >> 6, q = lane >> 4, c = lane & 15;
    int wave = blockIdx.x * 4 + wv, nw = gridDim.x * 4;
    for (int n = wave; n < N_NODES; n += nw) {
        int beg = off[n], end = off[n + 1];
        if (beg >= end) continue;
        float acc0 = 0.f, acc1 = 0.f, acc2 = 0.f, acc3 = 0.f;
        int sl0 = beg + c; if (sl0 >= end) sl0 = end - 1;
        int srcn = slot_s[sl0];                  // prefetched src for chunk 0
        #pragma unroll 1
        for (int base = beg; base < end; base += 16) {
            int slot = base + c;
            bool valid = slot < end;
            if (!valid) slot = end - 1;
            int scur = srcn;
            if (base + 16 < end) {               // prefetch next chunk's src
                int s2 = base + 16 + c; if (s2 >= end) s2 = end - 1;
                srcn = slot_s[s2];
            }
            const float4* dp = (const float4*)(DF + (size_t)slot * 64);  // streaming
            float4 d0 = dp[q*2],     d1 = dp[q*2 + 1];
            float4 d2 = dp[8 + q*2], d3 = dp[8 + q*2 + 1];
            const float4* cp = (const float4*)(CF + (size_t)scur * 64);  // gather (L2/L3 hot)
            float4 c0 = cp[q*2],     c1 = cp[q*2 + 1];
            float4 c2 = cp[8 + q*2], c3 = cp[8 + q*2 + 1];
            s8 ahi[2], alo[2];
            {
                float xs[8] = {c0.x*d0.x, c0.y*d0.y, c0.z*d0.z, c0.w*d0.w,
                               c1.x*d1.x, c1.y*d1.y, c1.z*d1.z, c1.w*d1.w};
                if (!valid) {
                    #pragma unroll
                    for (int j = 0; j < 8; ++j) xs[j] = 0.0f;
                }
                split8(xs, ahi[0], alo[0]);
                float ys[8] = {c2.x*d2.x, c2.y*d2.y, c2.z*d2.z, c2.w*d2.w,
                               c3.x*d3.x, c3.y*d3.y, c3.z*d3.z, c3.w*d3.w};
                if (!valid) {
                    #pragma unroll
                    for (int j = 0; j < 8; ++j) ys[j] = 0.0f;
                }
                split8(ys, ahi[1], alo[1]);
            }
            f4 d[4];
            #pragma unroll
            for (int g = 0; g < 4; ++g) d[g] = splat4(0.0f);
            #pragma unroll
            for (int ks = 0; ks < 2; ++ks)
                #pragma unroll
                for (int g = 0; g < 4; ++g) {
                    s8 wh = LW[(ks*4 + g) * 64 + lane];
                    s8 wl = LW[(8 + ks*4 + g) * 64 + lane];
                    d[g] = MFMA16(ahi[ks], wh, d[g]);
                    d[g] = MFMA16(ahi[ks], wl, d[g]);
                    d[g] = MFMA16(alo[ks], wh, d[g]);
                }
            // tail rows had zero A -> d=0 -> tanh(0)=0: safe to sum all regs
            acc0 += fast_tanh(d[0][0]) + fast_tanh(d[0][1]) + fast_tanh(d[0][2]) + fast_tanh(d[0][3]);
            acc1 += fast_tanh(d[1][0]) + fast_tanh(d[1][1]) + fast_tanh(d[1][2]) + fast_tanh(d[1][3]);
            acc2 += fast_tanh(d[2][0]) + fast_tanh(d[2][1]) + fast_tanh(d[2][2]) + fast_tanh(d[2][3]);
            acc3 += fast_tanh(d[3][0]) + fast_tanh(d[3][1]) + fast_tanh(d[3][2]) + fast_tanh(d[3][3]);
        }
        // reduce across the 4 lane-quads (edge-row subsets) — verified R3
        acc0 += __shfl_xor(acc0, 16, 64); acc0 += __shfl_xor(acc0, 32, 64);
        acc1 += __shfl_xor(acc1, 16, 64); acc1 += __shfl_xor(acc1, 32, 64);
        acc2 += __shfl_xor(acc2, 16, 64); acc2 += __shfl_xor(acc2, 32, 64);
        acc3 += __shfl_xor(acc3, 16, 64); acc3 += __shfl_xor(acc3, 32, 64);
        float v = (q == 0) ? acc0 : (q == 1) ? acc1 : (q == 2) ? acc2 : acc3;
        C[(size_t)n * 64 + lane] += v;
    }
}

// ---- fallback path (ws too small; never expected — kept for safety) ----
__global__ __launch_bounds__(256) void k_gemm64_fb(const float* __restrict__ in,
        const float* __restrict__ W, const float* __restrict__ b,
        float* __restrict__ out, int rows) {
    int r = blockIdx.x * blockDim.x + threadIdx.x;
    if (r >= rows) return;
    float acc[BASIS];
    #pragma unroll
    for (int c = 0; c < BASIS; ++c) acc[c] = b[c];
    const float4* in4 = (const float4*)(in + (size_t)r * BASIS);
    #pragma unroll 1
    for (int k0 = 0; k0 < 16; ++k0) {
        float4 xv = in4[k0];
        #pragma unroll
        for (int c = 0; c < BASIS; ++c)
            acc[c] += xv.x * W[(4*k0+0)*64+c] + xv.y * W[(4*k0+1)*64+c]
                    + xv.z * W[(4*k0+2)*64+c] + xv.w * W[(4*k0+3)*64+c];
    }
    #pragma unroll
    for (int c = 0; c < BASIS; ++c) out[(size_t)r * BASIS + c] = acc[c];
}
__global__ __launch_bounds__(256) void k_edge_fb(const float* __restrict__ CF,
        const float* __restrict__ ea, const float* __restrict__ dfW,
        const float* __restrict__ dfb, const float* __restrict__ fcW,
        const int* __restrict__ src, const int* __restrict__ dst,
        float* __restrict__ C) {
    int e = blockIdx.x * blockDim.x + threadIdx.x;
    if (e >= N_EDGES) return;
    int s = src[e], d = dst[e];
    float dfeat[BASIS];
    #pragma unroll
    for (int c = 0; c < BASIS; ++c) dfeat[c] = dfb[c];
    const float4* ea4 = (const float4*)(ea + (size_t)e * BASIS);
    #pragma unroll
    for (int k0 = 0; k0 < 16; ++k0) {
        float4 xv = ea4[k0];
        #pragma unroll
        for (int c = 0; c < BASIS; ++c)
            dfeat[c] += xv.x * dfW[(4*k0+0)*64+c] + xv.y * dfW[(4*k0+1)*64+c]
                      + xv.z * dfW[(4*k0+2)*64+c] + xv.w * dfW[(4*k0+3)*64+c];
    }
    const float4* cf4 = (const float4*)(CF + (size_t)s * BASIS);
    float acc[BASIS];
    #pragma unroll
    for (int c = 0; c < BASIS; ++c) acc[c] = 0.0f;
    #pragma unroll
    for (int k0 = 0; k0 < 16; ++k0) {
        float4 a = cf4[k0];
        float x0 = a.x * dfeat[4*k0+0], x1 = a.y * dfeat[4*k0+1];
        float x2 = a.z * dfeat[4*k0+2], x3 = a.w * dfeat[4*k0+3];
        #pragma unroll
        for (int c = 0; c < BASIS; ++c)
            acc[c] += x0 * fcW[(4*k0+0)*64+c] + x1 * fcW[(4*k0+1)*64+c]
                    + x2 * fcW[(4*k0+2)*64+c] + x3 * fcW[(4*k0+3)*64+c];
    }
    float* crow = C + (size_t)d * BASIS;
    #pragma unroll
    for (int c = 0; c < BASIS; ++c) atomicAdd(&crow[c], fast_tanh(acc[c]));
}

// ---- readout: wave per node, W1 in LDS ----
__global__ __launch_bounds__(256) void k_readout2(const float* __restrict__ C,
        const float* __restrict__ W1, const float* __restrict__ b1,
        const float* __restrict__ W2, const float* __restrict__ b2,
        const int* __restrict__ batch, float* __restrict__ out) {
    __shared__ float w1[BASIS * HIDDEN_RO];   // 32 KB
    __shared__ float xbuf[4][64];
    int t = threadIdx.x;
    for (int i = t; i < BASIS * HIDDEN_RO; i += 256) w1[i] = W1[i];
    __syncthreads();
    int lane = t & 63, wv = t >> 6;
    float b1a = b1[lane], b1b = b1[64 + lane];
    float4 w2a = ((const float4*)W2)[lane];
    float4 w2b = ((const float4*)W2)[64 + lane];
    int wave = blockIdx.x * 4 + wv;
    int nw   = gridDim.x * 4;
    for (int n = wave; n < N_NODES; n += nw) {
        float x = C[(size_t)n * 64 + lane];
        xbuf[wv][lane] = x;
        __builtin_amdgcn_wave_barrier();
        const float4* xb = (const float4*)xbuf[wv];
        float sa = b1a, sb = b1b;
        #pragma unroll
        for (int k4 = 0; k4 < 16; ++k4) {
            float4 xv = xb[k4];
            const float* r0 = &w1[(4*k4 + 0) * HIDDEN_RO];
            const float* r1 = &w1[(4*k4 + 1) * HIDDEN_RO];
            const float* r2 = &w1[(4*k4 + 2) * HIDDEN_RO];
            const float* r3 = &w1[(4*k4 + 3) * HIDDEN_RO];
            sa += xv.x * r0[lane]      + xv.y * r1[lane]
                + xv.z * r2[lane]      + xv.w * r3[lane];
            sb += xv.x * r0[64 + lane] + xv.y * r1[64 + lane]
                + xv.z * r2[64 + lane] + xv.w * r3[64 + lane];
        }
        float ha = fast_tanh(sa), hb = fast_tanh(sb);
        float v0 = ha * w2a.x + hb * w2b.x;
        float v1 = ha * w2a.y + hb * w2b.y;
        float v2 = ha * w2a.z + hb * w2b.z;
        float v3 = ha * w2a.w + hb * w2b.w;
        #pragma unroll
        for (int ofs = 32; ofs >= 1; ofs >>= 1) {
            v0 += __shfl_down(v0, ofs, 64);
            v1 += __shfl_down(v1, ofs, 64);
            v2 += __shfl_down(v2, ofs, 64);
            v3 += __shfl_down(v3, ofs, 64);
        }
        if (lane == 0) {
            int g = batch[n];
            atomicAdd(&out[(size_t)g * 4 + 0], v0);
            atomicAdd(&out[(size_t)g * 4 + 1], v1);
            atomicAdd(&out[(size_t)g * 4 + 2], v2);
            atomicAdd(&out[(size_t)g * 4 + 3], v3);
        }
        __builtin_amdgcn_wave_barrier();
    }
}

extern "C" void kernel_launch(void* const* d_in, const int* in_sizes, int n_in,
                              void* d_out, int out_size, void* d_ws, size_t ws_size,
                              hipStream_t stream) {
    // Z, edge_index, edge_attr, batch, embed, cfW, cfb, dfW, dfb, fcW, W1, b1, W2, b2
    const int*   Z     = (const int*)d_in[0];
    const int*   ei    = (const int*)d_in[1];
    const float* ea    = (const float*)d_in[2];
    const int*   batch = (const int*)d_in[3];
    const float* embed = (const float*)d_in[4];
    const float* cfW   = (const float*)d_in[5];
    const float* cfb   = (const float*)d_in[6];
    const float* dfW   = (const float*)d_in[7];
    const float* dfb   = (const float*)d_in[8];
    const float* fcW   = (const float*)d_in[9];
    const float* W1    = (const float*)d_in[10];
    const float* b1    = (const float*)d_in[11];
    const float* W2    = (const float*)d_in[12];
    const float* b2    = (const float*)d_in[13];
    const int* src = ei;
    const int* dst = ei + N_EDGES;
    float* out = (float*)d_out;

    const size_t bC = (size_t)N_NODES * BASIS * sizeof(float);   // 12.8 MB
    const size_t bE = (size_t)N_EDGES * sizeof(int);             // 3.2 MB
    const size_t bO = (size_t)(N_NODES + 1) * sizeof(int);
    const size_t bI = 1024 * sizeof(s8);                         // 16 KB per W image
    char* p = (char*)d_ws;
    float* C      = (float*)p;  p += bC;
    float* CF     = (float*)p;  p += bC;
    int*   slotE  = (int*)p;    p += bE;
    int*   slotS  = (int*)p;    p += bE;
    int*   deg    = (int*)p;    p += bO;
    int*   off    = (int*)p;    p += bO;
    int*   cursor = (int*)p;    p += bO;
    p = (char*)(((uintptr_t)p + 255) & ~(uintptr_t)255);
    s8* imgDF = (s8*)p;  p += bI;
    s8* imgCF = (s8*)p;  p += bI;
    s8* imgFC = (s8*)p;  p += bI;
    float* DF = (float*)p;
    const size_t need = (size_t)(p - (char*)d_ws) + (size_t)N_EDGES * BASIS * sizeof(float);
    const bool full = ws_size >= need;   // ~237 MB — held every prior round

    hipMemsetAsync(d_out, 0, (size_t)out_size * sizeof(float), stream);

    if (full) {
        hipMemsetAsync(deg, 0, bO, stream);
        k_init_hist<<<(N_NODES * BASIS + 255) / 256, 256, 0, stream>>>(Z, embed, C, dst, deg);
        k_packW<<<3, 256, 0, stream>>>(dfW, cfW, fcW, imgDF, imgCF, imgFC);
        k_scan<<<1, 1024, 0, stream>>>(deg, off, cursor);
        k_fill<<<(N_EDGES + 255) / 256, 256, 0, stream>>>(src, dst, cursor, slotE, slotS);
        k_gemm64L<1><<<4096, 256, 0, stream>>>(ea, imgDF, dfb, slotE, DF, N_EDGES);
        for (int t = 0; t < T_ITERS; ++t) {
            k_gemm64L<0><<<800, 256, 0, stream>>>(C, imgCF, cfb, nullptr, CF, N_NODES);
            k_mp5<<<2048, 256, 0, stream>>>(CF, DF, imgFC, slotS, off, C);
        }
    } else {
        // minimal fallback: C + CF only (25.6 MB)
        k_init_hist<<<(N_NODES * BASIS + 255) / 256, 256, 0, stream>>>(Z, embed, C, dst, (int*)CF);
        for (int t = 0; t < T_ITERS; ++t) {
            k_gemm64_fb<<<(N_NODES + 255) / 256, 256, 0, stream>>>(C, cfW, cfb, CF, N_NODES);
            k_edge_fb<<<(N_EDGES + 255) / 256, 256, 0, stream>>>(CF, ea, dfW, dfb, fcW, src, dst, C);
        }
    }

    k_readout2<<<512, 256, 0, stream>>>(C, W1, b1, W2, b2, batch, out);
}